// Round 8
// baseline (387.857 us; speedup 1.0000x reference)
//
#include <hip/hip_runtime.h>

#define ZN 131072          // B*H*W rows
#define DD 64              // embedding dim
#define KK 1024            // codebook entries
#define BSTRIDE 262144     // 64*64*64 (per-batch stride in z)
#define DSTRIDE 4096       // per-d stride in z (H*W)
#define ZQ_ELEMS 8388608   // 32*64*64*64
#define TAU 2e-4f

// ---- workspace layout ----
// [0,8)                double   loss accumulator
// [8,12)               unsigned done-block counter
// [12,16)              unsigned pair count
// [16,20)              unsigned overflow-row count
// [32,4128)            float    csq32[1024]    (numpy-emulated fp32)
// [4128,528416)        float    zsq32[131072]  (numpy-emulated fp32)
// [528416,1052704)     int      ovflist[131072]
// [1052704,2101280)    u64      pack[131072]   (ordered_dist<<32 | k)
// [2363408,2625552)    ushort   cbB[64][2][2][64][8]  bf16 hi/lo B-fragments
// [2625552, +8MB)      u32      pairs[] = (n<<10 | k) candidate list
#define WS_CSQ_OFF   32
#define WS_ZSQ_OFF   4128
#define WS_OVF_OFF   528416
#define WS_PACK_OFF  1052704
#define WS_CBB_OFF   2363408
#define WS_PAIR_OFF  2625552
#define PAIR_CAP     2097152u

typedef __attribute__((ext_vector_type(8))) short short8;
typedef __attribute__((ext_vector_type(4))) float f32x4;

// round-to-nearest-even fp32 -> bf16 (data has no NaN/Inf)
__device__ __forceinline__ unsigned short f2bf_rne(float x) {
    unsigned u = __float_as_uint(x);
    return (unsigned short)((u + 0x7fffu + ((u >> 16) & 1u)) >> 16);
}

// numpy-emulated fp32 sum of a[i]^2 over 64 elems (pairwise, 8 accumulators).
__device__ __forceinline__ float np_sumsq64(const float* a) {
    float r0 = __fmul_rn(a[0], a[0]), r1 = __fmul_rn(a[1], a[1]);
    float r2 = __fmul_rn(a[2], a[2]), r3 = __fmul_rn(a[3], a[3]);
    float r4 = __fmul_rn(a[4], a[4]), r5 = __fmul_rn(a[5], a[5]);
    float r6 = __fmul_rn(a[6], a[6]), r7 = __fmul_rn(a[7], a[7]);
#pragma unroll
    for (int i = 8; i < 64; i += 8) {
        r0 = __fadd_rn(r0, __fmul_rn(a[i + 0], a[i + 0]));
        r1 = __fadd_rn(r1, __fmul_rn(a[i + 1], a[i + 1]));
        r2 = __fadd_rn(r2, __fmul_rn(a[i + 2], a[i + 2]));
        r3 = __fadd_rn(r3, __fmul_rn(a[i + 3], a[i + 3]));
        r4 = __fadd_rn(r4, __fmul_rn(a[i + 4], a[i + 4]));
        r5 = __fadd_rn(r5, __fmul_rn(a[i + 5], a[i + 5]));
        r6 = __fadd_rn(r6, __fmul_rn(a[i + 6], a[i + 6]));
        r7 = __fadd_rn(r7, __fmul_rn(a[i + 7], a[i + 7]));
    }
    return __fadd_rn(__fadd_rn(__fadd_rn(r0, r1), __fadd_rn(r2, r3)),
                     __fadd_rn(__fadd_rn(r4, r5), __fadd_rn(r6, r7)));
}

// Merged: csq (numpy fp32) + bf16 hi/lo B-fragment prep + counter zeroing.
// B frag for v_mfma_f32_16x16x32_bf16: col = lane&15, k = (lane>>4)*8 + j.
__global__ __launch_bounds__(256) void vq_prep(const float* __restrict__ cb,
                                               float* __restrict__ csq,
                                               unsigned short* __restrict__ cbB,
                                               double* __restrict__ acc,
                                               unsigned* __restrict__ ctrs) {
    if (blockIdx.x == 0 && threadIdx.x < 3) {
        if (threadIdx.x == 0) *acc = 0.0;
        ctrs[threadIdx.x] = 0u;   // done, paircnt, ovfcnt
    }
    int k = blockIdx.x * 256 + threadIdx.x;
    const float* cp = cb + k * DD;
    csq[k] = np_sumsq64(cp);
    int ct = k >> 4, col = k & 15;
#pragma unroll
    for (int d = 0; d < DD; ++d) {
        float c = cp[d];
        unsigned short hi = f2bf_rne(c);
        float hf = __uint_as_float((unsigned)hi << 16);
        unsigned short lo = f2bf_rne(c - hf);
        int s = d >> 5, lg = (d >> 3) & 3, j = d & 7;
        int lane = col + 16 * lg;
        int base = ct * 2048 + s * 512 + lane * 8 + j;
        cbB[base] = hi;          // h = 0
        cbB[base + 1024] = lo;   // h = 1
    }
}

// numpy-emulated fp32 ||z||^2 per row (needed by pair refine).
__global__ __launch_bounds__(256) void vq_zsq(const float* __restrict__ z,
                                              float* __restrict__ zsq32) {
    int n = blockIdx.x * 256 + threadIdx.x;
    int b = n >> 12, p = n & 4095;
    const float* zp = z + (size_t)b * BSTRIDE + p;
    float r[8];
#pragma unroll
    for (int j = 0; j < 8; ++j) {
        float v = zp[(size_t)j * DSTRIDE];
        r[j] = __fmul_rn(v, v);
    }
#pragma unroll
    for (int i = 8; i < 64; i += 8)
#pragma unroll
        for (int j = 0; j < 8; ++j) {
            float v = zp[(size_t)(i + j) * DSTRIDE];
            r[j] = __fadd_rn(r[j], __fmul_rn(v, v));
        }
    zsq32[n] = __fadd_rn(__fadd_rn(__fadd_rn(r[0], r[1]), __fadd_rn(r[2], r[3])),
                         __fadd_rn(__fadd_rn(r[4], r[5]), __fadd_rn(r[6], r[7])));
}

// dist computation: two independent 3-chains.
#define MFMA_DIST(P, Q, A_H0, A_H1, A_L0, A_L1, B0, B1, B2, B3)               \
    P = __builtin_amdgcn_mfma_f32_16x16x32_bf16(A_H0, B0, P, 0, 0, 0);        \
    Q = __builtin_amdgcn_mfma_f32_16x16x32_bf16(A_H0, B2, Q, 0, 0, 0);        \
    P = __builtin_amdgcn_mfma_f32_16x16x32_bf16(A_H1, B1, P, 0, 0, 0);        \
    Q = __builtin_amdgcn_mfma_f32_16x16x32_bf16(A_H1, B3, Q, 0, 0, 0);        \
    P = __builtin_amdgcn_mfma_f32_16x16x32_bf16(A_L0, B0, P, 0, 0, 0);        \
    Q = __builtin_amdgcn_mfma_f32_16x16x32_bf16(A_L1, B1, Q, 0, 0, 0);

// -------- MFMA bf16^3 scan + ballot candidate extraction --------
// block = 64 rows = 4 waves; wave w owns rows [16w,16w+16), scans all 1024
// codes. r4 loop body (register min1/min2/bst, phase-locked every 8 ct) +
// r2 codegen (waves_per_eu(2) for register headroom, depth-1 B prefetch).
// Post-loop (r7-validated): g1 = 16-lane butterfly; candidates = lane-bests
// with m1 < g1+TAU (ballot+popcount, zero atomics); guard ballot m2 < g1+TAU
// detects a possible non-lane-best winner -> overflow full-1024 fp64 row.
// Error budget: |mfma-ref| <= ~1e-5; a ref winner w has mfma(w) <= g1+2e-5
// << g1+TAU, so candidates+overflow form a superset of all ref winners.
// cnt==1 & no guard: every other code x has mfma(x) >= g1+TAU -> ref(x) >
// ref(w) strictly -> resolved without fp64.
__global__ __attribute__((amdgpu_waves_per_eu(2))) __launch_bounds__(256)
void vq_scan(const float* __restrict__ z,
             const unsigned short* __restrict__ cbB,
             const float* __restrict__ csq,
             float* __restrict__ idxf_out,
             unsigned* __restrict__ ctrs,   // [0]=done [1]=paircnt [2]=ovfcnt
             unsigned* __restrict__ pairs,
             int* __restrict__ ovflist,
             unsigned paircap,
             unsigned long long* __restrict__ pack) {
    __shared__ __align__(16) unsigned short aFrag[4][2][2][64][8];  // [rt][s][h][lane][j]
    __shared__ float scsq[1024];
    __shared__ int candCnt[64];
    __shared__ unsigned short candK[64][16];
    __shared__ unsigned char ovfF[64];

    int t = threadIdx.x;
    int n0 = blockIdx.x * 64;
    int b = n0 >> 12, p0 = n0 & 4095;   // 64 | 4096 -> no batch crossing in block

    for (int i = t; i < 1024; i += 256) scsq[i] = csq[i];
    if (t < 64) pack[n0 + t] = ~0ull;   // default: no fp64 override

    {   // stage z tile: thread t loads row r = t&63, d-groups g = 2*(t>>6)+{0,1}
        int r = t & 63, gb = t >> 6;
        const float* zp = z + (size_t)b * BSTRIDE + p0 + r;
#pragma unroll
        for (int gg = 0; gg < 2; ++gg) {
            int g = (gb << 1) | gg;  // d in [8g, 8g+8)
            short8 hi8, lo8;
#pragma unroll
            for (int i2 = 0; i2 < 8; ++i2) {
                float v = zp[(size_t)(8 * g + i2) * DSTRIDE];  // coalesced across lanes
                unsigned short h = f2bf_rne(v);
                float hf = __uint_as_float((unsigned)h << 16);
                hi8[i2] = (short)h;
                lo8[i2] = (short)f2bf_rne(v - hf);
            }
            int rt = r >> 4, s = g >> 2, lane = (r & 15) + 16 * (g & 3);
            *(short8*)&aFrag[rt][s][0][lane][0] = hi8;
            *(short8*)&aFrag[rt][s][1][lane][0] = lo8;
        }
    }
    __syncthreads();

    int l = t & 63;
    int colcode = l & 15;
    int w = __builtin_amdgcn_readfirstlane(t >> 6);  // wave id = row-tile

    short8 aH0 = *(const short8*)&aFrag[w][0][0][l][0];
    short8 aH1 = *(const short8*)&aFrag[w][1][0][l][0];
    short8 aL0 = *(const short8*)&aFrag[w][0][1][l][0];
    short8 aL1 = *(const short8*)&aFrag[w][1][1][l][0];

    float m1[4], m2[4];
    int bst[4];
#pragma unroll
    for (int r = 0; r < 4; ++r) {
        m1[r] = 3.4e38f;
        m2[r] = 3.4e38f;
        bst[r] = 0;
    }

    // ---- hot loop: r4 body + depth-1 register B prefetch ----
    const unsigned short* bpb = cbB + (l << 3);
    short8 nb0 = *(const short8*)(bpb);
    short8 nb1 = *(const short8*)(bpb + 512);
    short8 nb2 = *(const short8*)(bpb + 1024);
    short8 nb3 = *(const short8*)(bpb + 1536);
    for (int ph = 0; ph < 8; ++ph) {
        __syncthreads();  // phase-lock the 4 waves for L1 B-frag reuse
#pragma unroll 2
        for (int c8 = 0; c8 < 8; ++c8) {
            int ct = (ph << 3) | c8;
            short8 b0 = nb0, b1 = nb1, b2 = nb2, b3 = nb3;
            if (ct < 63) {
                const unsigned short* np = bpb + (ct + 1) * 2048;
                nb0 = *(const short8*)(np);
                nb1 = *(const short8*)(np + 512);
                nb2 = *(const short8*)(np + 1024);
                nb3 = *(const short8*)(np + 1536);
            }
            float cs = scsq[(ct << 4) + colcode];
            int code = (ct << 4) + colcode;
            f32x4 p = {0.f, 0.f, 0.f, 0.f}, q = {0.f, 0.f, 0.f, 0.f};
            MFMA_DIST(p, q, aH0, aH1, aL0, aL1, b0, b1, b2, b3)
#pragma unroll
            for (int r = 0; r < 4; ++r) {
                float dist = fmaf(-2.f, p[r] + q[r], cs);
                bool lt = dist < m1[r];  // strict: ties keep lowest code
                m2[r] = lt ? m1[r] : fminf(m2[r], dist);
                bst[r] = lt ? code : bst[r];
                m1[r] = lt ? dist : m1[r];
            }
        }
    }

    // ---- candidate extraction: g1 butterfly + ballots (r7-validated) ----
    int g = l >> 4;  // lane group; lanes [16g,16g+16) share rows 4g+0..4g+3
#pragma unroll
    for (int r = 0; r < 4; ++r) {
        float v = m1[r];
        v = fminf(v, __shfl_xor(v, 1, 64));
        v = fminf(v, __shfl_xor(v, 2, 64));
        v = fminf(v, __shfl_xor(v, 4, 64));
        v = fminf(v, __shfl_xor(v, 8, 64));
        float thr = v + TAU;
        bool mine = (m1[r] < thr);
        unsigned long long bal1 = __ballot(mine);
        unsigned long long bal2 = __ballot(m2[r] < thr);
        unsigned slice1 = (unsigned)((bal1 >> (16 * g)) & 0xFFFFull);
        unsigned slice2 = (unsigned)((bal2 >> (16 * g)) & 0xFFFFull);
        int row = (w << 4) + (g << 2) + r;
        if (mine) {
            int pos = __popc(slice1 & ((1u << colcode) - 1u));
            candK[row][pos] = (unsigned short)bst[r];
        }
        if (colcode == 0) {
            candCnt[row] = __popc(slice1);
            ovfF[row] = (slice2 != 0u) ? 1 : 0;
        }
    }
    __syncthreads();

    // ---- flush: resolve single-candidate rows; compact the rest ----
    if (t < 64) {
        int cnt = candCnt[t];
        bool ovf = (ovfF[t] != 0);
        bool resolved = (cnt == 1 && !ovf);
        if (resolved) idxf_out[n0 + t] = (float)candK[t][0];
        int cc = (ovf || resolved) ? 0 : cnt;
        int run = cc;  // inclusive prefix over 64 lanes
#pragma unroll
        for (int off = 1; off < 64; off <<= 1) {
            int o = __shfl_up(run, off, 64);
            if (t >= off) run += o;
        }
        int total = __shfl(run, 63, 64);
        unsigned base = 0;
        if (t == 63 && total) base = atomicAdd(&ctrs[1], (unsigned)total);
        base = __shfl(base, 63, 64);
        bool fits = (base <= paircap) && (base + (unsigned)total <= paircap);
        bool toOvf = ovf || (!resolved && !fits);
        unsigned long long mb = __ballot(toOvf);
        int otot = __popcll(mb);
        unsigned obase = 0;
        if (t == 0 && otot) obase = atomicAdd(&ctrs[2], (unsigned)otot);
        obase = __shfl(obase, 0, 64);
        if (toOvf) {
            int opre = __popcll(mb & ((1ull << t) - 1ull));
            ovflist[obase + opre] = n0 + t;
        } else if (!resolved) {
            unsigned st = base + (unsigned)(run - cc);
            unsigned nn = (unsigned)(n0 + t) << 10;
            for (int i = 0; i < cnt; ++i)
                pairs[st + i] = nn | candK[t][i];
        }
    }
}

// fp64 reference-fp32-emulated distance (bit-identical to the validated
// refine of earlier rounds) -> order-preserving packed u64 (ties -> lowest k).
__device__ __forceinline__ unsigned long long ref_pack(const float* zp,
                                                       const float* cp,
                                                       float zsqn, float csqk,
                                                       unsigned k) {
    double a0 = 0.0, a1 = 0.0, a2 = 0.0, a3 = 0.0;
#pragma unroll
    for (int d = 0; d < DD; d += 4) {
        a0 = fma((double)zp[(size_t)(d + 0) * DSTRIDE], (double)cp[d + 0], a0);
        a1 = fma((double)zp[(size_t)(d + 1) * DSTRIDE], (double)cp[d + 1], a1);
        a2 = fma((double)zp[(size_t)(d + 2) * DSTRIDE], (double)cp[d + 2], a2);
        a3 = fma((double)zp[(size_t)(d + 3) * DSTRIDE], (double)cp[d + 3], a3);
    }
    double dot = (a0 + a1) + (a2 + a3);
    float twoC = (float)(2.0 * dot);               // ~sgemm output, correctly rounded
    float dist = __fsub_rn(__fadd_rn(zsqn, csqk), twoC);  // reference fp32 ops
    unsigned ub = __float_as_uint(dist);
    ub = (ub & 0x80000000u) ? ~ub : (ub | 0x80000000u);   // order-preserving map
    return ((unsigned long long)ub << 32) | k;
}

// -------- exact refine over candidate pairs + overflow rows (r6) --------
__global__ __launch_bounds__(256) void vq_refine_pairs(
    const float* __restrict__ z,
    const float* __restrict__ cb,
    const float* __restrict__ csq,
    const float* __restrict__ zsq32,
    const unsigned* __restrict__ ctrs,
    const unsigned* __restrict__ pairs,
    const int* __restrict__ ovflist,
    unsigned paircap,
    unsigned long long* __restrict__ pack) {
    unsigned stride = gridDim.x * 256;
    unsigned tid = blockIdx.x * 256 + threadIdx.x;

    unsigned cnt = ctrs[1];
    if (cnt > paircap) cnt = paircap;
    for (unsigned i = tid; i < cnt; i += stride) {
        unsigned pr = pairs[i];
        unsigned n = pr >> 10;
        if (n < (unsigned)ZN) {
            unsigned k = pr & 1023u;
            int b = n >> 12, p = n & 4095;
            const float* zp = z + (size_t)b * BSTRIDE + p;
            unsigned long long pk =
                ref_pack(zp, cb + k * DD, zsq32[n], csq[k], k);
            atomicMin(&pack[n], pk);
        }
    }

    // overflow rows: full 1024-code exact scan
    unsigned long long tot2 = (unsigned long long)ctrs[2] << 10;
    for (unsigned long long wk = tid; wk < tot2; wk += stride) {
        unsigned r = (unsigned)(wk >> 10);
        unsigned k = (unsigned)(wk & 1023u);
        int n = ovflist[r];
        int b = n >> 12, p = n & 4095;
        const float* zp = z + (size_t)b * BSTRIDE + p;
        unsigned long long pk = ref_pack(zp, cb + k * DD, zsq32[n], csq[k], k);
        atomicMin(&pack[n], pk);
    }
}

// -------- gather z_q + idx writeback + loss + device-side finalize --------
__global__ __launch_bounds__(256) void vq_gather_loss(const float* __restrict__ z,
                                                      const float* __restrict__ cb,
                                                      const unsigned long long* __restrict__ pack,
                                                      float* __restrict__ idxf,
                                                      float* __restrict__ zq_out,
                                                      float* __restrict__ loss_out,
                                                      double* __restrict__ acc,
                                                      unsigned* __restrict__ ctrs) {
    int n = blockIdx.x * 256 + threadIdx.x;
    int b = n >> 12, p = n & 4095;
    const float* zp = z + (size_t)b * BSTRIDE + p;
    float* qp = zq_out + (size_t)b * BSTRIDE + p;

    unsigned long long pk = pack[n];
    int k = (pk != ~0ull) ? (int)(unsigned)(pk & 1023ull) : (int)idxf[n];
    idxf[n] = (float)k;
    const float* c = cb + k * DD;

    float s = 0.f;
#pragma unroll
    for (int d = 0; d < DD; ++d) {
        float q = c[d];
        float diff = q - zp[(size_t)d * DSTRIDE];
        s = fmaf(diff, diff, s);
        qp[(size_t)d * DSTRIDE] = q;  // z_q_st == z_q numerically
    }

#pragma unroll
    for (int off = 32; off; off >>= 1) s += __shfl_down(s, off, 64);
    __shared__ float partial[4];
    if ((threadIdx.x & 63) == 0) partial[threadIdx.x >> 6] = s;
    __syncthreads();
    if (threadIdx.x == 0) {
        float t = (partial[0] + partial[1]) + (partial[2] + partial[3]);
        atomicAdd(acc, (double)t);
        __threadfence();
        unsigned v = atomicAdd(&ctrs[0], 1u);
        if (v == gridDim.x - 1) {           // last block finalizes the loss
            __threadfence();
            double s2 = atomicAdd(acc, 0.0);
            *loss_out = (float)(1.25 * s2 / (double)ZQ_ELEMS);
        }
    }
}

extern "C" void kernel_launch(void* const* d_in, const int* in_sizes, int n_in,
                              void* d_out, int out_size, void* d_ws, size_t ws_size,
                              hipStream_t stream) {
    const float* z = (const float*)d_in[0];
    const float* cb = (const float*)d_in[1];
    float* out = (float*)d_out;

    float* zq_out = out;                   // [0, 8388608)
    float* loss_out = out + ZQ_ELEMS;      // [8388608]
    float* idxf_out = out + ZQ_ELEMS + 1;  // [8388609, +131072)

    char* ws = (char*)d_ws;
    double* acc = (double*)ws;
    unsigned* ctrs = (unsigned*)(ws + 8);  // done, paircnt, ovfcnt
    float* csq = (float*)(ws + WS_CSQ_OFF);
    float* zsq32 = (float*)(ws + WS_ZSQ_OFF);
    int* ovflist = (int*)(ws + WS_OVF_OFF);
    unsigned long long* pack = (unsigned long long*)(ws + WS_PACK_OFF);
    unsigned short* cbB = (unsigned short*)(ws + WS_CBB_OFF);
    unsigned* pairs = (unsigned*)(ws + WS_PAIR_OFF);

    unsigned paircap = 0;
    if (ws_size > WS_PAIR_OFF)
        paircap = (unsigned)((ws_size - WS_PAIR_OFF) / 4);
    if (paircap > PAIR_CAP) paircap = PAIR_CAP;

    vq_prep<<<KK / 256, 256, 0, stream>>>(cb, csq, cbB, acc, ctrs);
    vq_zsq<<<ZN / 256, 256, 0, stream>>>(z, zsq32);
    vq_scan<<<ZN / 64, 256, 0, stream>>>(z, cbB, csq, idxf_out, ctrs,
                                         pairs, ovflist, paircap, pack);
    vq_refine_pairs<<<512, 256, 0, stream>>>(z, cb, csq, zsq32, ctrs,
                                             pairs, ovflist, paircap, pack);
    vq_gather_loss<<<ZN / 256, 256, 0, stream>>>(z, cb, pack, idxf_out, zq_out,
                                                 loss_out, acc, ctrs);
}

// Round 9
// 312.695 us; speedup vs baseline: 1.2404x; 1.2404x over previous
//
#include <hip/hip_runtime.h>

#define ZN 131072          // B*H*W rows
#define DD 64              // embedding dim
#define KK 1024            // codebook entries
#define BSTRIDE 262144     // 64*64*64 (per-batch stride in z)
#define DSTRIDE 4096       // per-d stride in z (H*W)
#define ZQ_ELEMS 8388608   // 32*64*64*64
#define TAU 2e-4f

// ---- workspace layout ----
// [0,8)                double   loss accumulator
// [8,16)               unsigned ctrs[2]: done-block counter, ambiguous-row count
// [32,4128)            float    csq32[1024]    (numpy-emulated fp32)
// [528416,1052704)     u32      rowinfo[131072]  (n | cnt<<17 | ovf<<22)
// [1052704,2101280)    u64      pack[131072]   (ordered_dist<<32 | k)
// [2363408,2625552)    ushort   cbB[64][2][2][64][8]  bf16 hi/lo B-fragments
// [2625552, +4MB)      u16      candbuf[slot][16] candidate codes
#define WS_CSQ_OFF   32
#define WS_ROW_OFF   528416
#define WS_PACK_OFF  1052704
#define WS_CBB_OFF   2363408
#define WS_CAND_OFF  2625552

typedef __attribute__((ext_vector_type(8))) short short8;
typedef __attribute__((ext_vector_type(4))) float f32x4;

// round-to-nearest-even fp32 -> bf16 (data has no NaN/Inf)
__device__ __forceinline__ unsigned short f2bf_rne(float x) {
    unsigned u = __float_as_uint(x);
    return (unsigned short)((u + 0x7fffu + ((u >> 16) & 1u)) >> 16);
}

// numpy-emulated fp32 sum of a[i]^2 over 64 elems (pairwise, 8 accumulators).
__device__ __forceinline__ float np_sumsq64(const float* a) {
    float r0 = __fmul_rn(a[0], a[0]), r1 = __fmul_rn(a[1], a[1]);
    float r2 = __fmul_rn(a[2], a[2]), r3 = __fmul_rn(a[3], a[3]);
    float r4 = __fmul_rn(a[4], a[4]), r5 = __fmul_rn(a[5], a[5]);
    float r6 = __fmul_rn(a[6], a[6]), r7 = __fmul_rn(a[7], a[7]);
#pragma unroll
    for (int i = 8; i < 64; i += 8) {
        r0 = __fadd_rn(r0, __fmul_rn(a[i + 0], a[i + 0]));
        r1 = __fadd_rn(r1, __fmul_rn(a[i + 1], a[i + 1]));
        r2 = __fadd_rn(r2, __fmul_rn(a[i + 2], a[i + 2]));
        r3 = __fadd_rn(r3, __fmul_rn(a[i + 3], a[i + 3]));
        r4 = __fadd_rn(r4, __fmul_rn(a[i + 4], a[i + 4]));
        r5 = __fadd_rn(r5, __fmul_rn(a[i + 5], a[i + 5]));
        r6 = __fadd_rn(r6, __fmul_rn(a[i + 6], a[i + 6]));
        r7 = __fadd_rn(r7, __fmul_rn(a[i + 7], a[i + 7]));
    }
    return __fadd_rn(__fadd_rn(__fadd_rn(r0, r1), __fadd_rn(r2, r3)),
                     __fadd_rn(__fadd_rn(r4, r5), __fadd_rn(r6, r7)));
}

// Merged: csq (numpy fp32) + bf16 hi/lo B-fragment prep + counter zeroing.
// B frag for v_mfma_f32_16x16x32_bf16: col = lane&15, k = (lane>>4)*8 + j.
__global__ __launch_bounds__(256) void vq_prep(const float* __restrict__ cb,
                                               float* __restrict__ csq,
                                               unsigned short* __restrict__ cbB,
                                               double* __restrict__ acc,
                                               unsigned* __restrict__ ctrs) {
    if (blockIdx.x == 0 && threadIdx.x < 2) {
        if (threadIdx.x == 0) *acc = 0.0;
        ctrs[threadIdx.x] = 0u;   // done, rowcnt
    }
    int k = blockIdx.x * 256 + threadIdx.x;
    const float* cp = cb + k * DD;
    csq[k] = np_sumsq64(cp);
    int ct = k >> 4, col = k & 15;
#pragma unroll
    for (int d = 0; d < DD; ++d) {
        float c = cp[d];
        unsigned short hi = f2bf_rne(c);
        float hf = __uint_as_float((unsigned)hi << 16);
        unsigned short lo = f2bf_rne(c - hf);
        int s = d >> 5, lg = (d >> 3) & 3, j = d & 7;
        int lane = col + 16 * lg;
        int base = ct * 2048 + s * 512 + lane * 8 + j;
        cbB[base] = hi;          // h = 0
        cbB[base + 1024] = lo;   // h = 1
    }
}

// dist computation: two independent 3-chains.
#define MFMA_DIST(P, Q, A_H0, A_H1, A_L0, A_L1, B0, B1, B2, B3)               \
    P = __builtin_amdgcn_mfma_f32_16x16x32_bf16(A_H0, B0, P, 0, 0, 0);        \
    Q = __builtin_amdgcn_mfma_f32_16x16x32_bf16(A_H0, B2, Q, 0, 0, 0);        \
    P = __builtin_amdgcn_mfma_f32_16x16x32_bf16(A_H1, B1, P, 0, 0, 0);        \
    Q = __builtin_amdgcn_mfma_f32_16x16x32_bf16(A_H1, B3, Q, 0, 0, 0);        \
    P = __builtin_amdgcn_mfma_f32_16x16x32_bf16(A_L0, B0, P, 0, 0, 0);        \
    Q = __builtin_amdgcn_mfma_f32_16x16x32_bf16(A_L1, B1, Q, 0, 0, 0);

// -------- MFMA bf16^3 scan + ballot candidate extraction (r8, unchanged
// except the flush now emits rowinfo+candbuf instead of flat pairs) --------
__global__ __attribute__((amdgpu_waves_per_eu(2))) __launch_bounds__(256)
void vq_scan(const float* __restrict__ z,
             const unsigned short* __restrict__ cbB,
             const float* __restrict__ csq,
             float* __restrict__ idxf_out,
             unsigned* __restrict__ ctrs,   // [0]=done [1]=rowcnt
             unsigned* __restrict__ rowinfo,
             unsigned short* __restrict__ candbuf,
             unsigned candcap,
             unsigned long long* __restrict__ pack) {
    __shared__ __align__(16) unsigned short aFrag[4][2][2][64][8];  // [rt][s][h][lane][j]
    __shared__ float scsq[1024];
    __shared__ int candCnt[64];
    __shared__ unsigned short candK[64][16];
    __shared__ unsigned char ovfF[64];

    int t = threadIdx.x;
    int n0 = blockIdx.x * 64;
    int b = n0 >> 12, p0 = n0 & 4095;   // 64 | 4096 -> no batch crossing in block

    for (int i = t; i < 1024; i += 256) scsq[i] = csq[i];
    if (t < 64) pack[n0 + t] = ~0ull;   // default: no fp64 override

    {   // stage z tile: thread t loads row r = t&63, d-groups g = 2*(t>>6)+{0,1}
        int r = t & 63, gb = t >> 6;
        const float* zp = z + (size_t)b * BSTRIDE + p0 + r;
#pragma unroll
        for (int gg = 0; gg < 2; ++gg) {
            int g = (gb << 1) | gg;  // d in [8g, 8g+8)
            short8 hi8, lo8;
#pragma unroll
            for (int i2 = 0; i2 < 8; ++i2) {
                float v = zp[(size_t)(8 * g + i2) * DSTRIDE];  // coalesced across lanes
                unsigned short h = f2bf_rne(v);
                float hf = __uint_as_float((unsigned)h << 16);
                hi8[i2] = (short)h;
                lo8[i2] = (short)f2bf_rne(v - hf);
            }
            int rt = r >> 4, s = g >> 2, lane = (r & 15) + 16 * (g & 3);
            *(short8*)&aFrag[rt][s][0][lane][0] = hi8;
            *(short8*)&aFrag[rt][s][1][lane][0] = lo8;
        }
    }
    __syncthreads();

    int l = t & 63;
    int colcode = l & 15;
    int w = __builtin_amdgcn_readfirstlane(t >> 6);  // wave id = row-tile

    short8 aH0 = *(const short8*)&aFrag[w][0][0][l][0];
    short8 aH1 = *(const short8*)&aFrag[w][1][0][l][0];
    short8 aL0 = *(const short8*)&aFrag[w][0][1][l][0];
    short8 aL1 = *(const short8*)&aFrag[w][1][1][l][0];

    float m1[4], m2[4];
    int bst[4];
#pragma unroll
    for (int r = 0; r < 4; ++r) {
        m1[r] = 3.4e38f;
        m2[r] = 3.4e38f;
        bst[r] = 0;
    }

    // ---- hot loop: r4 body + depth-1 register B prefetch ----
    const unsigned short* bpb = cbB + (l << 3);
    short8 nb0 = *(const short8*)(bpb);
    short8 nb1 = *(const short8*)(bpb + 512);
    short8 nb2 = *(const short8*)(bpb + 1024);
    short8 nb3 = *(const short8*)(bpb + 1536);
    for (int ph = 0; ph < 8; ++ph) {
        __syncthreads();  // phase-lock the 4 waves for L1 B-frag reuse
#pragma unroll 2
        for (int c8 = 0; c8 < 8; ++c8) {
            int ct = (ph << 3) | c8;
            short8 b0 = nb0, b1 = nb1, b2 = nb2, b3 = nb3;
            if (ct < 63) {
                const unsigned short* np = bpb + (ct + 1) * 2048;
                nb0 = *(const short8*)(np);
                nb1 = *(const short8*)(np + 512);
                nb2 = *(const short8*)(np + 1024);
                nb3 = *(const short8*)(np + 1536);
            }
            float cs = scsq[(ct << 4) + colcode];
            int code = (ct << 4) + colcode;
            f32x4 p = {0.f, 0.f, 0.f, 0.f}, q = {0.f, 0.f, 0.f, 0.f};
            MFMA_DIST(p, q, aH0, aH1, aL0, aL1, b0, b1, b2, b3)
#pragma unroll
            for (int r = 0; r < 4; ++r) {
                float dist = fmaf(-2.f, p[r] + q[r], cs);
                bool lt = dist < m1[r];  // strict: ties keep lowest code
                m2[r] = lt ? m1[r] : fminf(m2[r], dist);
                bst[r] = lt ? code : bst[r];
                m1[r] = lt ? dist : m1[r];
            }
        }
    }

    // ---- candidate extraction: g1 butterfly + ballots (r7-validated) ----
    int g = l >> 4;  // lane group; lanes [16g,16g+16) share rows 4g+0..4g+3
#pragma unroll
    for (int r = 0; r < 4; ++r) {
        float v = m1[r];
        v = fminf(v, __shfl_xor(v, 1, 64));
        v = fminf(v, __shfl_xor(v, 2, 64));
        v = fminf(v, __shfl_xor(v, 4, 64));
        v = fminf(v, __shfl_xor(v, 8, 64));
        float thr = v + TAU;
        bool mine = (m1[r] < thr);
        unsigned long long bal1 = __ballot(mine);
        unsigned long long bal2 = __ballot(m2[r] < thr);
        unsigned slice1 = (unsigned)((bal1 >> (16 * g)) & 0xFFFFull);
        unsigned slice2 = (unsigned)((bal2 >> (16 * g)) & 0xFFFFull);
        int row = (w << 4) + (g << 2) + r;
        if (mine) {
            int pos = __popc(slice1 & ((1u << colcode) - 1u));
            candK[row][pos] = (unsigned short)bst[r];
        }
        if (colcode == 0) {
            candCnt[row] = __popc(slice1);
            ovfF[row] = (slice2 != 0u) ? 1 : 0;
        }
    }
    __syncthreads();

    // ---- flush: resolve single-candidate rows; compact ambiguous rows ----
    if (t < 64) {
        int cnt = candCnt[t];
        bool ovf = (ovfF[t] != 0);
        bool resolved = (cnt == 1 && !ovf);
        if (resolved) idxf_out[n0 + t] = (float)candK[t][0];
        bool amb = !resolved;
        unsigned long long mb = __ballot(amb);
        int tot = __popcll(mb);
        unsigned base = 0;
        if (t == 0 && tot) base = atomicAdd(&ctrs[1], (unsigned)tot);
        base = __shfl(base, 0, 64);
        if (amb) {
            unsigned slot = base + (unsigned)__popcll(mb & ((1ull << t) - 1ull));
            bool fits = (slot < candcap);
            unsigned useOvf = (ovf || !fits) ? 1u : 0u;
            unsigned ccnt = useOvf ? 0u : (unsigned)cnt;
            rowinfo[slot] = (unsigned)(n0 + t) | (ccnt << 17) | (useOvf << 22);
            if (!useOvf)
                for (int i = 0; i < cnt; ++i)
                    candbuf[slot * 16 + i] = candK[t][i];
        }
    }
}

// fp64 reference-fp32-emulated distance on a CONTIGUOUS copy of the z row
// (identical values, identical op order to the validated strided ref_pack)
// -> order-preserving packed u64 (ties -> lowest k).
__device__ __forceinline__ unsigned long long ref_pack_c(const float* zr,
                                                         const float* cp,
                                                         float zsqn, float csqk,
                                                         unsigned k) {
    double a0 = 0.0, a1 = 0.0, a2 = 0.0, a3 = 0.0;
#pragma unroll
    for (int d = 0; d < DD; d += 4) {
        a0 = fma((double)zr[d + 0], (double)cp[d + 0], a0);
        a1 = fma((double)zr[d + 1], (double)cp[d + 1], a1);
        a2 = fma((double)zr[d + 2], (double)cp[d + 2], a2);
        a3 = fma((double)zr[d + 3], (double)cp[d + 3], a3);
    }
    double dot = (a0 + a1) + (a2 + a3);
    float twoC = (float)(2.0 * dot);               // ~sgemm output, correctly rounded
    float dist = __fsub_rn(__fadd_rn(zsqn, csqk), twoC);  // reference fp32 ops
    unsigned ub = __float_as_uint(dist);
    ub = (ub & 0x80000000u) ? ~ub : (ub | 0x80000000u);   // order-preserving map
    return ((unsigned long long)ub << 32) | k;
}

// -------- wave-per-row exact refine --------
// One wave per ambiguous row. The 64 lanes stage the strided z row into LDS
// with a single vector load (64 cachelines in flight at once -> one latency,
// not 64 serial), then zsq is computed from the LDS copy (numpy pairwise
// order -> bit-identical to the former vq_zsq), and each lane fp64-scores
// one candidate (cnt<=16) or 16 codes (ovf row, full 1024). Wave-min reduce,
// lane 0 plain-stores pack[n] (rows unique). Loop bound is wave-uniform ->
// all 64 lanes active at the LDS handshake (s_waitcnt lgkmcnt).
__global__ __launch_bounds__(256) void vq_refine2(
    const float* __restrict__ z,
    const float* __restrict__ cb,
    const float* __restrict__ csq,
    const unsigned* __restrict__ ctrs,
    const unsigned* __restrict__ rowinfo,
    const unsigned short* __restrict__ candbuf,
    unsigned long long* __restrict__ pack) {
    __shared__ float zrow[4][64];
    int l = threadIdx.x & 63;
    int wv = threadIdx.x >> 6;
    unsigned nrows = ctrs[1];
    unsigned nwaves = gridDim.x * 4;

    for (unsigned s = blockIdx.x * 4 + wv; s < nrows; s += nwaves) {
        unsigned info = rowinfo[s];
        unsigned n = info & 0x1FFFFu;
        unsigned cnt = (info >> 17) & 0x1Fu;
        bool ovf = ((info >> 22) & 1u) != 0u;
        int b = n >> 12, p = n & 4095;
        const float* zp = z + (size_t)b * BSTRIDE + p;

        zrow[wv][l] = zp[(size_t)l * DSTRIDE];   // 64 cachelines, one issue
        asm volatile("s_waitcnt lgkmcnt(0)" ::: "memory");

        float zsqn = np_sumsq64(&zrow[wv][0]);   // numpy order, bit-identical

        unsigned long long pk = ~0ull;
        if (ovf) {
#pragma unroll
            for (int c = 0; c < 16; ++c) {
                unsigned k = (unsigned)(c * 64 + l);
                unsigned long long v =
                    ref_pack_c(&zrow[wv][0], cb + k * DD, zsqn, csq[k], k);
                pk = (v < pk) ? v : pk;
            }
        } else if ((unsigned)l < cnt) {
            unsigned k = candbuf[s * 16 + l];
            pk = ref_pack_c(&zrow[wv][0], cb + k * DD, zsqn, csq[k], k);
        }
#pragma unroll
        for (int off = 32; off; off >>= 1) {
            unsigned long long o =
                (unsigned long long)__shfl_xor((long long)pk, off, 64);
            pk = (o < pk) ? o : pk;
        }
        if (l == 0) pack[n] = pk;   // unique row per slot: plain store
    }
}

// -------- gather z_q + idx writeback + loss + device-side finalize --------
__global__ __launch_bounds__(256) void vq_gather_loss(const float* __restrict__ z,
                                                      const float* __restrict__ cb,
                                                      const unsigned long long* __restrict__ pack,
                                                      float* __restrict__ idxf,
                                                      float* __restrict__ zq_out,
                                                      float* __restrict__ loss_out,
                                                      double* __restrict__ acc,
                                                      unsigned* __restrict__ ctrs) {
    int n = blockIdx.x * 256 + threadIdx.x;
    int b = n >> 12, p = n & 4095;
    const float* zp = z + (size_t)b * BSTRIDE + p;
    float* qp = zq_out + (size_t)b * BSTRIDE + p;

    unsigned long long pk = pack[n];
    int k = (pk != ~0ull) ? (int)(unsigned)(pk & 1023ull) : (int)idxf[n];
    idxf[n] = (float)k;
    const float* c = cb + k * DD;

    float s = 0.f;
#pragma unroll
    for (int d = 0; d < DD; ++d) {
        float q = c[d];
        float diff = q - zp[(size_t)d * DSTRIDE];
        s = fmaf(diff, diff, s);
        qp[(size_t)d * DSTRIDE] = q;  // z_q_st == z_q numerically
    }

#pragma unroll
    for (int off = 32; off; off >>= 1) s += __shfl_down(s, off, 64);
    __shared__ float partial[4];
    if ((threadIdx.x & 63) == 0) partial[threadIdx.x >> 6] = s;
    __syncthreads();
    if (threadIdx.x == 0) {
        float t = (partial[0] + partial[1]) + (partial[2] + partial[3]);
        atomicAdd(acc, (double)t);
        __threadfence();
        unsigned v = atomicAdd(&ctrs[0], 1u);
        if (v == gridDim.x - 1) {           // last block finalizes the loss
            __threadfence();
            double s2 = atomicAdd(acc, 0.0);
            *loss_out = (float)(1.25 * s2 / (double)ZQ_ELEMS);
        }
    }
}

extern "C" void kernel_launch(void* const* d_in, const int* in_sizes, int n_in,
                              void* d_out, int out_size, void* d_ws, size_t ws_size,
                              hipStream_t stream) {
    const float* z = (const float*)d_in[0];
    const float* cb = (const float*)d_in[1];
    float* out = (float*)d_out;

    float* zq_out = out;                   // [0, 8388608)
    float* loss_out = out + ZQ_ELEMS;      // [8388608]
    float* idxf_out = out + ZQ_ELEMS + 1;  // [8388609, +131072)

    char* ws = (char*)d_ws;
    double* acc = (double*)ws;
    unsigned* ctrs = (unsigned*)(ws + 8);  // done, rowcnt
    float* csq = (float*)(ws + WS_CSQ_OFF);
    unsigned* rowinfo = (unsigned*)(ws + WS_ROW_OFF);
    unsigned long long* pack = (unsigned long long*)(ws + WS_PACK_OFF);
    unsigned short* cbB = (unsigned short*)(ws + WS_CBB_OFF);
    unsigned short* candbuf = (unsigned short*)(ws + WS_CAND_OFF);

    unsigned candcap = 0;  // rows that fit their 16-code lists in candbuf
    if (ws_size > WS_CAND_OFF)
        candcap = (unsigned)((ws_size - WS_CAND_OFF) / 32);
    if (candcap > (unsigned)ZN) candcap = (unsigned)ZN;

    vq_prep<<<KK / 256, 256, 0, stream>>>(cb, csq, cbB, acc, ctrs);
    vq_scan<<<ZN / 64, 256, 0, stream>>>(z, cbB, csq, idxf_out, ctrs,
                                         rowinfo, candbuf, candcap, pack);
    vq_refine2<<<512, 256, 0, stream>>>(z, cb, csq, ctrs, rowinfo, candbuf, pack);
    vq_gather_loss<<<ZN / 256, 256, 0, stream>>>(z, cb, pack, idxf_out, zq_out,
                                                 loss_out, acc, ctrs);
}

// Round 11
// 311.456 us; speedup vs baseline: 1.2453x; 1.0040x over previous
//
#include <hip/hip_runtime.h>

#define ZN 131072          // B*H*W rows
#define DD 64              // embedding dim
#define KK 1024            // codebook entries
#define BSTRIDE 262144     // 64*64*64 (per-batch stride in z)
#define DSTRIDE 4096       // per-d stride in z (H*W)
#define ZQ_ELEMS 8388608   // 32*64*64*64
#define TAU 2e-4f

// ---- workspace layout ----
// [0,8)                double   loss accumulator
// [8,16)               unsigned ctrs[2]: done-block counter, ambiguous-row count
// [32,4128)            float    csq32[1024]    (numpy-emulated fp32)
// [528416,1052704)     u32      rowinfo[131072]  (n | cnt<<17 | ovf<<22)
// [1052704,2101280)    u64      pack[131072]   (ordered_dist<<32 | k)
// [2363408,2625552)    ushort   cbB[64][2][2][64][8]  bf16 hi/lo B-fragments
// [2625552, +4MB)      u16      candbuf[slot][16] candidate codes
#define WS_CSQ_OFF   32
#define WS_ROW_OFF   528416
#define WS_PACK_OFF  1052704
#define WS_CBB_OFF   2363408
#define WS_CAND_OFF  2625552

typedef __attribute__((ext_vector_type(8))) short short8;
typedef __attribute__((ext_vector_type(4))) float f32x4;

// round-to-nearest-even fp32 -> bf16 (data has no NaN/Inf)
__device__ __forceinline__ unsigned short f2bf_rne(float x) {
    unsigned u = __float_as_uint(x);
    return (unsigned short)((u + 0x7fffu + ((u >> 16) & 1u)) >> 16);
}

// numpy-emulated fp32 sum of a[i]^2 over 64 elems (pairwise, 8 accumulators).
__device__ __forceinline__ float np_sumsq64(const float* a) {
    float r0 = __fmul_rn(a[0], a[0]), r1 = __fmul_rn(a[1], a[1]);
    float r2 = __fmul_rn(a[2], a[2]), r3 = __fmul_rn(a[3], a[3]);
    float r4 = __fmul_rn(a[4], a[4]), r5 = __fmul_rn(a[5], a[5]);
    float r6 = __fmul_rn(a[6], a[6]), r7 = __fmul_rn(a[7], a[7]);
#pragma unroll
    for (int i = 8; i < 64; i += 8) {
        r0 = __fadd_rn(r0, __fmul_rn(a[i + 0], a[i + 0]));
        r1 = __fadd_rn(r1, __fmul_rn(a[i + 1], a[i + 1]));
        r2 = __fadd_rn(r2, __fmul_rn(a[i + 2], a[i + 2]));
        r3 = __fadd_rn(r3, __fmul_rn(a[i + 3], a[i + 3]));
        r4 = __fadd_rn(r4, __fmul_rn(a[i + 4], a[i + 4]));
        r5 = __fadd_rn(r5, __fmul_rn(a[i + 5], a[i + 5]));
        r6 = __fadd_rn(r6, __fmul_rn(a[i + 6], a[i + 6]));
        r7 = __fadd_rn(r7, __fmul_rn(a[i + 7], a[i + 7]));
    }
    return __fadd_rn(__fadd_rn(__fadd_rn(r0, r1), __fadd_rn(r2, r3)),
                     __fadd_rn(__fadd_rn(r4, r5), __fadd_rn(r6, r7)));
}

// Merged: csq (numpy fp32) + bf16 hi/lo B-fragment prep + counter zeroing.
// B frag for v_mfma_f32_16x16x32_bf16: col = lane&15, k = (lane>>4)*8 + j.
__global__ __launch_bounds__(256) void vq_prep(const float* __restrict__ cb,
                                               float* __restrict__ csq,
                                               unsigned short* __restrict__ cbB,
                                               double* __restrict__ acc,
                                               unsigned* __restrict__ ctrs) {
    if (blockIdx.x == 0 && threadIdx.x < 2) {
        if (threadIdx.x == 0) *acc = 0.0;
        ctrs[threadIdx.x] = 0u;   // done, rowcnt
    }
    int k = blockIdx.x * 256 + threadIdx.x;
    const float* cp = cb + k * DD;
    csq[k] = np_sumsq64(cp);
    int ct = k >> 4, col = k & 15;
#pragma unroll
    for (int d = 0; d < DD; ++d) {
        float c = cp[d];
        unsigned short hi = f2bf_rne(c);
        float hf = __uint_as_float((unsigned)hi << 16);
        unsigned short lo = f2bf_rne(c - hf);
        int s = d >> 5, lg = (d >> 3) & 3, j = d & 7;
        int lane = col + 16 * lg;
        int base = ct * 2048 + s * 512 + lane * 8 + j;
        cbB[base] = hi;          // h = 0
        cbB[base + 1024] = lo;   // h = 1
    }
}

// dist computation: two independent 3-chains.
#define MFMA_DIST(P, Q, A_H0, A_H1, A_L0, A_L1, B0, B1, B2, B3)               \
    P = __builtin_amdgcn_mfma_f32_16x16x32_bf16(A_H0, B0, P, 0, 0, 0);        \
    Q = __builtin_amdgcn_mfma_f32_16x16x32_bf16(A_H0, B2, Q, 0, 0, 0);        \
    P = __builtin_amdgcn_mfma_f32_16x16x32_bf16(A_H1, B1, P, 0, 0, 0);        \
    Q = __builtin_amdgcn_mfma_f32_16x16x32_bf16(A_H1, B3, Q, 0, 0, 0);        \
    P = __builtin_amdgcn_mfma_f32_16x16x32_bf16(A_L0, B0, P, 0, 0, 0);        \
    Q = __builtin_amdgcn_mfma_f32_16x16x32_bf16(A_L1, B1, Q, 0, 0, 0);

// -------- MFMA bf16^3 scan + ballot candidate extraction (r9-validated,
// byte-identical) --------
__global__ __attribute__((amdgpu_waves_per_eu(2))) __launch_bounds__(256)
void vq_scan(const float* __restrict__ z,
             const unsigned short* __restrict__ cbB,
             const float* __restrict__ csq,
             float* __restrict__ idxf_out,
             unsigned* __restrict__ ctrs,   // [0]=done [1]=rowcnt
             unsigned* __restrict__ rowinfo,
             unsigned short* __restrict__ candbuf,
             unsigned candcap,
             unsigned long long* __restrict__ pack) {
    __shared__ __align__(16) unsigned short aFrag[4][2][2][64][8];  // [rt][s][h][lane][j]
    __shared__ float scsq[1024];
    __shared__ int candCnt[64];
    __shared__ unsigned short candK[64][16];
    __shared__ unsigned char ovfF[64];

    int t = threadIdx.x;
    int n0 = blockIdx.x * 64;
    int b = n0 >> 12, p0 = n0 & 4095;   // 64 | 4096 -> no batch crossing in block

    for (int i = t; i < 1024; i += 256) scsq[i] = csq[i];
    if (t < 64) pack[n0 + t] = ~0ull;   // default: no fp64 override

    {   // stage z tile: thread t loads row r = t&63, d-groups g = 2*(t>>6)+{0,1}
        int r = t & 63, gb = t >> 6;
        const float* zp = z + (size_t)b * BSTRIDE + p0 + r;
#pragma unroll
        for (int gg = 0; gg < 2; ++gg) {
            int g = (gb << 1) | gg;  // d in [8g, 8g+8)
            short8 hi8, lo8;
#pragma unroll
            for (int i2 = 0; i2 < 8; ++i2) {
                float v = zp[(size_t)(8 * g + i2) * DSTRIDE];  // coalesced across lanes
                unsigned short h = f2bf_rne(v);
                float hf = __uint_as_float((unsigned)h << 16);
                hi8[i2] = (short)h;
                lo8[i2] = (short)f2bf_rne(v - hf);
            }
            int rt = r >> 4, s = g >> 2, lane = (r & 15) + 16 * (g & 3);
            *(short8*)&aFrag[rt][s][0][lane][0] = hi8;
            *(short8*)&aFrag[rt][s][1][lane][0] = lo8;
        }
    }
    __syncthreads();

    int l = t & 63;
    int colcode = l & 15;
    int w = __builtin_amdgcn_readfirstlane(t >> 6);  // wave id = row-tile

    short8 aH0 = *(const short8*)&aFrag[w][0][0][l][0];
    short8 aH1 = *(const short8*)&aFrag[w][1][0][l][0];
    short8 aL0 = *(const short8*)&aFrag[w][0][1][l][0];
    short8 aL1 = *(const short8*)&aFrag[w][1][1][l][0];

    float m1[4], m2[4];
    int bst[4];
#pragma unroll
    for (int r = 0; r < 4; ++r) {
        m1[r] = 3.4e38f;
        m2[r] = 3.4e38f;
        bst[r] = 0;
    }

    // ---- hot loop: r4 body + depth-1 register B prefetch ----
    const unsigned short* bpb = cbB + (l << 3);
    short8 nb0 = *(const short8*)(bpb);
    short8 nb1 = *(const short8*)(bpb + 512);
    short8 nb2 = *(const short8*)(bpb + 1024);
    short8 nb3 = *(const short8*)(bpb + 1536);
    for (int ph = 0; ph < 8; ++ph) {
        __syncthreads();  // phase-lock the 4 waves for L1 B-frag reuse
#pragma unroll 2
        for (int c8 = 0; c8 < 8; ++c8) {
            int ct = (ph << 3) | c8;
            short8 b0 = nb0, b1 = nb1, b2 = nb2, b3 = nb3;
            if (ct < 63) {
                const unsigned short* np = bpb + (ct + 1) * 2048;
                nb0 = *(const short8*)(np);
                nb1 = *(const short8*)(np + 512);
                nb2 = *(const short8*)(np + 1024);
                nb3 = *(const short8*)(np + 1536);
            }
            float cs = scsq[(ct << 4) + colcode];
            int code = (ct << 4) + colcode;
            f32x4 p = {0.f, 0.f, 0.f, 0.f}, q = {0.f, 0.f, 0.f, 0.f};
            MFMA_DIST(p, q, aH0, aH1, aL0, aL1, b0, b1, b2, b3)
#pragma unroll
            for (int r = 0; r < 4; ++r) {
                float dist = fmaf(-2.f, p[r] + q[r], cs);
                bool lt = dist < m1[r];  // strict: ties keep lowest code
                m2[r] = lt ? m1[r] : fminf(m2[r], dist);
                bst[r] = lt ? code : bst[r];
                m1[r] = lt ? dist : m1[r];
            }
        }
    }

    // ---- candidate extraction: g1 butterfly + ballots (r7-validated) ----
    int g = l >> 4;  // lane group; lanes [16g,16g+16) share rows 4g+0..4g+3
#pragma unroll
    for (int r = 0; r < 4; ++r) {
        float v = m1[r];
        v = fminf(v, __shfl_xor(v, 1, 64));
        v = fminf(v, __shfl_xor(v, 2, 64));
        v = fminf(v, __shfl_xor(v, 4, 64));
        v = fminf(v, __shfl_xor(v, 8, 64));
        float thr = v + TAU;
        bool mine = (m1[r] < thr);
        unsigned long long bal1 = __ballot(mine);
        unsigned long long bal2 = __ballot(m2[r] < thr);
        unsigned slice1 = (unsigned)((bal1 >> (16 * g)) & 0xFFFFull);
        unsigned slice2 = (unsigned)((bal2 >> (16 * g)) & 0xFFFFull);
        int row = (w << 4) + (g << 2) + r;
        if (mine) {
            int pos = __popc(slice1 & ((1u << colcode) - 1u));
            candK[row][pos] = (unsigned short)bst[r];
        }
        if (colcode == 0) {
            candCnt[row] = __popc(slice1);
            ovfF[row] = (slice2 != 0u) ? 1 : 0;
        }
    }
    __syncthreads();

    // ---- flush: resolve single-candidate rows; compact ambiguous rows ----
    if (t < 64) {
        int cnt = candCnt[t];
        bool ovf = (ovfF[t] != 0);
        bool resolved = (cnt == 1 && !ovf);
        if (resolved) idxf_out[n0 + t] = (float)candK[t][0];
        bool amb = !resolved;
        unsigned long long mb = __ballot(amb);
        int tot = __popcll(mb);
        unsigned base = 0;
        if (t == 0 && tot) base = atomicAdd(&ctrs[1], (unsigned)tot);
        base = __shfl(base, 0, 64);
        if (amb) {
            unsigned slot = base + (unsigned)__popcll(mb & ((1ull << t) - 1ull));
            bool fits = (slot < candcap);
            unsigned useOvf = (ovf || !fits) ? 1u : 0u;
            unsigned ccnt = useOvf ? 0u : (unsigned)cnt;
            rowinfo[slot] = (unsigned)(n0 + t) | (ccnt << 17) | (useOvf << 22);
            if (!useOvf)
                for (int i = 0; i < cnt; ++i)
                    candbuf[slot * 16 + i] = candK[t][i];
        }
    }
}

// fp64 reference-fp32-emulated distance on a CONTIGUOUS copy of the z row
// (identical values, identical op order to the validated strided ref_pack)
// -> order-preserving packed u64 (ties -> lowest k).
__device__ __forceinline__ unsigned long long ref_pack_c(const float* zr,
                                                         const float* cp,
                                                         float zsqn, float csqk,
                                                         unsigned k) {
    double a0 = 0.0, a1 = 0.0, a2 = 0.0, a3 = 0.0;
#pragma unroll
    for (int d = 0; d < DD; d += 4) {
        a0 = fma((double)zr[d + 0], (double)cp[d + 0], a0);
        a1 = fma((double)zr[d + 1], (double)cp[d + 1], a1);
        a2 = fma((double)zr[d + 2], (double)cp[d + 2], a2);
        a3 = fma((double)zr[d + 3], (double)cp[d + 3], a3);
    }
    double dot = (a0 + a1) + (a2 + a3);
    float twoC = (float)(2.0 * dot);               // ~sgemm output, correctly rounded
    float dist = __fsub_rn(__fadd_rn(zsqn, csqk), twoC);  // reference fp32 ops
    unsigned ub = __float_as_uint(dist);
    ub = (ub & 0x80000000u) ? ~ub : (ub | 0x80000000u);   // order-preserving map
    return ((unsigned long long)ub << 32) | k;
}

// -------- wave-per-row exact refine (r9-validated, unchanged) --------
__global__ __launch_bounds__(256) void vq_refine2(
    const float* __restrict__ z,
    const float* __restrict__ cb,
    const float* __restrict__ csq,
    const unsigned* __restrict__ ctrs,
    const unsigned* __restrict__ rowinfo,
    const unsigned short* __restrict__ candbuf,
    unsigned long long* __restrict__ pack) {
    __shared__ float zrow[4][64];
    int l = threadIdx.x & 63;
    int wv = threadIdx.x >> 6;
    unsigned nrows = ctrs[1];
    unsigned nwaves = gridDim.x * 4;

    for (unsigned s = blockIdx.x * 4 + wv; s < nrows; s += nwaves) {
        unsigned info = rowinfo[s];
        unsigned n = info & 0x1FFFFu;
        unsigned cnt = (info >> 17) & 0x1Fu;
        bool ovf = ((info >> 22) & 1u) != 0u;
        int b = n >> 12, p = n & 4095;
        const float* zp = z + (size_t)b * BSTRIDE + p;

        zrow[wv][l] = zp[(size_t)l * DSTRIDE];   // 64 cachelines, one issue
        asm volatile("s_waitcnt lgkmcnt(0)" ::: "memory");

        float zsqn = np_sumsq64(&zrow[wv][0]);   // numpy order, bit-identical

        unsigned long long pk = ~0ull;
        if (ovf) {
#pragma unroll
            for (int c = 0; c < 16; ++c) {
                unsigned k = (unsigned)(c * 64 + l);
                unsigned long long v =
                    ref_pack_c(&zrow[wv][0], cb + k * DD, zsqn, csq[k], k);
                pk = (v < pk) ? v : pk;
            }
        } else if ((unsigned)l < cnt) {
            unsigned k = candbuf[s * 16 + l];
            pk = ref_pack_c(&zrow[wv][0], cb + k * DD, zsqn, csq[k], k);
        }
#pragma unroll
        for (int off = 32; off; off >>= 1) {
            unsigned long long o =
                (unsigned long long)__shfl_xor((long long)pk, off, 64);
            pk = (o < pk) ? o : pk;
        }
        if (l == 0) pack[n] = pk;   // unique row per slot: plain store
    }
}

// -------- gather z_q + idx writeback + loss + device-side finalize --------
// THE ONLY CHANGE THIS ROUND: codebook rows staged into LDS COALESCED (wave
// reads cb[k][lane]: one contiguous 256B load per row) instead of the
// per-thread 64-cacheline divergent gather. Stride padded to 65 floats
// (2-way bank aliasing on both phases = free). Values bit-identical.
__global__ __launch_bounds__(256) void vq_gather_loss(const float* __restrict__ z,
                                                      const float* __restrict__ cb,
                                                      const unsigned long long* __restrict__ pack,
                                                      float* __restrict__ idxf,
                                                      float* __restrict__ zq_out,
                                                      float* __restrict__ loss_out,
                                                      double* __restrict__ acc,
                                                      unsigned* __restrict__ ctrs) {
    __shared__ float scb[256][65];
    __shared__ int skey[256];
    __shared__ float partial[4];

    int t = threadIdx.x;
    int n = blockIdx.x * 256 + t;

    unsigned long long pk = pack[n];
    int k = (pk != ~0ull) ? (int)(unsigned)(pk & 1023ull) : (int)idxf[n];
    idxf[n] = (float)k;
    skey[t] = k;
    __syncthreads();

    int l = t & 63, wv = t >> 6;
    for (int i = 0; i < 64; ++i) {          // wave wv stages rows [64wv, 64wv+64)
        int row = (wv << 6) + i;
        scb[row][l] = cb[skey[row] * DD + l];  // coalesced 256B, L2-hot
    }
    __syncthreads();

    int b = n >> 12, p = n & 4095;
    const float* zp = z + (size_t)b * BSTRIDE + p;
    float* qp = zq_out + (size_t)b * BSTRIDE + p;

    float s = 0.f;
#pragma unroll
    for (int d = 0; d < DD; ++d) {
        float qv = scb[t][d];
        float diff = qv - zp[(size_t)d * DSTRIDE];
        s = fmaf(diff, diff, s);
        qp[(size_t)d * DSTRIDE] = qv;  // z_q_st == z_q numerically
    }

#pragma unroll
    for (int off = 32; off; off >>= 1) s += __shfl_down(s, off, 64);
    if (l == 0) partial[wv] = s;
    __syncthreads();
    if (t == 0) {
        float tt = (partial[0] + partial[1]) + (partial[2] + partial[3]);
        atomicAdd(acc, (double)tt);
        __threadfence();
        unsigned v = atomicAdd(&ctrs[0], 1u);
        if (v == gridDim.x - 1) {           // last block finalizes the loss
            __threadfence();
            double s2 = atomicAdd(acc, 0.0);
            *loss_out = (float)(1.25 * s2 / (double)ZQ_ELEMS);
        }
    }
}

extern "C" void kernel_launch(void* const* d_in, const int* in_sizes, int n_in,
                              void* d_out, int out_size, void* d_ws, size_t ws_size,
                              hipStream_t stream) {
    const float* z = (const float*)d_in[0];
    const float* cb = (const float*)d_in[1];
    float* out = (float*)d_out;

    float* zq_out = out;                   // [0, 8388608)
    float* loss_out = out + ZQ_ELEMS;      // [8388608]
    float* idxf_out = out + ZQ_ELEMS + 1;  // [8388609, +131072)

    char* ws = (char*)d_ws;
    double* acc = (double*)ws;
    unsigned* ctrs = (unsigned*)(ws + 8);  // done, rowcnt
    float* csq = (float*)(ws + WS_CSQ_OFF);
    unsigned* rowinfo = (unsigned*)(ws + WS_ROW_OFF);
    unsigned long long* pack = (unsigned long long*)(ws + WS_PACK_OFF);
    unsigned short* cbB = (unsigned short*)(ws + WS_CBB_OFF);
    unsigned short* candbuf = (unsigned short*)(ws + WS_CAND_OFF);

    unsigned candcap = 0;  // rows that fit their 16-code lists in candbuf
    if (ws_size > WS_CAND_OFF)
        candcap = (unsigned)((ws_size - WS_CAND_OFF) / 32);
    if (candcap > (unsigned)ZN) candcap = (unsigned)ZN;

    vq_prep<<<KK / 256, 256, 0, stream>>>(cb, csq, cbB, acc, ctrs);
    vq_scan<<<ZN / 64, 256, 0, stream>>>(z, cbB, csq, idxf_out, ctrs,
                                         rowinfo, candbuf, candcap, pack);
    vq_refine2<<<512, 256, 0, stream>>>(z, cb, csq, ctrs, rowinfo, candbuf, pack);
    vq_gather_loss<<<ZN / 256, 256, 0, stream>>>(z, cb, pack, idxf_out, zq_out,
                                                 loss_out, acc, ctrs);
}